// Round 4
// baseline (11.761 us; speedup 1.0000x reference)
//
#include <hip/hip_runtime.h>
#include <hip/hip_bf16.h>
#include <math.h>

// PoincareMLR via algebraic reduction + bf16 MFMA for the two batched dots.
//   s_raw = <point_k, x_b>, t = <a_k, x_b>   (MFMA, bf16 in / f32 acc)
//   U2=|x_b|^2, cc=tanh(|point|)/|point|, P2=cc^2|point|^2, PA=cc<point,a>, AN=|a|  (fp32)
//   alpha=1-2s+U2, beta=1-P2, gamma=max(1-2s+P2*U2,EPS), s=cc*s_raw
//   |diff|^2=(alpha^2 P2 - 2 alpha beta s + beta^2 U2)/gamma^2
//   <diff,a>=(beta t - alpha PA)/gamma
//   logit = asinh(2<diff,a>/clamp_abs((1-|diff|^2)AN)) * AN
//
// R4: compiler-cast bf16 conversion (v_cvt_pk_bf16_f32 instead of ~4 VALU/elt
// integer RNE), batched global loads before the convert/store pass,
// nontemporal output stores. Structure otherwise as R3.

constexpr int D   = 256;   // feature dim
constexpr int BT  = 32;    // b rows per block
constexpr int KT  = 32;    // k rows per block
constexpr int S   = 264;   // LDS row stride in bf16 (+16B pad -> conflict-free b128)
constexpr float EPS = 1e-15f;

typedef __attribute__((ext_vector_type(8))) short short8;
typedef __attribute__((ext_vector_type(4))) float f32x4;

__device__ __forceinline__ ushort f2bf(float f) {
    union { __hip_bfloat16 h; ushort u; } cv;
    cv.h = __float2bfloat16(f);               // RNE; compiler emits v_cvt_pk_bf16_f32
    return cv.u;
}
__device__ __forceinline__ ushort4 bf4(float4 v) {
    return make_ushort4(f2bf(v.x), f2bf(v.y), f2bf(v.z), f2bf(v.w));
}
__device__ __forceinline__ float dot4(float4 a, float4 b) {
    return a.x * b.x + a.y * b.y + a.z * b.z + a.w * b.w;
}

__device__ __forceinline__ float epilogue(float s_raw, float t_raw, float U2,
                                          float cc, float P2, float PA, float AN) {
    float s     = cc * s_raw;
    float alpha = 1.f - 2.f * s + U2;
    float beta  = 1.f - P2;
    float gamma = fmaxf(1.f - 2.f * s + P2 * U2, EPS);
    float rg    = __builtin_amdgcn_rcpf(gamma);
    float nn    = alpha * alpha * P2 - 2.f * alpha * beta * s + beta * beta * U2;
    float dn2   = fmaxf(nn * rg * rg, EPS);
    float sc    = (beta * t_raw - alpha * PA) * rg;
    float draw  = (1.f - dn2) * AN;
    float den   = (draw >= 0.f ? 1.f : -1.f) * fmaxf(fabsf(draw), EPS);
    float z     = 2.f * sc * __builtin_amdgcn_rcpf(den);
    float az    = fabsf(z);
    // asinh(az) = log2(az + sqrt(az^2+1)) * ln2
    float r = __builtin_amdgcn_logf(az + __builtin_amdgcn_sqrtf(__builtin_fmaf(az, az, 1.f)))
              * 0.6931471805599453f;
    return (z >= 0.f ? r : -r) * AN;
}

__global__ __launch_bounds__(512, 2)
void poincare_mlr_kernel(const float* __restrict__ X,   // [B, D]
                         const float* __restrict__ P,   // [K, D] point
                         const float* __restrict__ A,   // [K, D] tangent
                         float* __restrict__ out,       // [B, K]
                         int K) {
    __shared__ ushort xs[BT * S];
    __shared__ ushort ps[KT * S];
    __shared__ ushort as_[KT * S];
    __shared__ float U2s[BT];
    __shared__ float kcc[KT], kP2[KT], kPA[KT], kAN[KT];

    const int tid = threadIdx.x;
    const int kb  = blockIdx.x & 3;          // K/KT = 4 k-tiles
    const int bb  = blockIdx.x >> 2;
    const int b0g = bb * BT;
    const int k0g = kb * KT;

    // ---- fused staging + per-row scalars (single global read) ----
    // thread (rx, g): rx = tid>>4 in [0,32), g = tid&15. Owns 4 float4 chunks
    // (cols g+16t) of X row rx, P row rx, A row rx.
    {
        const int rx = tid >> 4, g = tid & 15;
        const float4* Xr = (const float4*)(X + (size_t)(b0g + rx) * D);
        const float4* Pr = (const float4*)(P + (size_t)(k0g + rx) * D);
        const float4* Ar = (const float4*)(A + (size_t)(k0g + rx) * D);

        // issue all 12 loads first (one latency wait instead of 12)
        float4 vx[4], vp[4], va[4];
        #pragma unroll
        for (int t = 0; t < 4; ++t) {
            const int c = g + 16 * t;
            vx[t] = Xr[c];
            vp[t] = Pr[c];
            va[t] = Ar[c];
        }

        float x2 = 0.f, n2 = 0.f, pa = 0.f, a2 = 0.f;
        #pragma unroll
        for (int t = 0; t < 4; ++t) {
            const int c = g + 16 * t;
            x2 += dot4(vx[t], vx[t]);
            n2 += dot4(vp[t], vp[t]);
            pa += dot4(vp[t], va[t]);
            a2 += dot4(va[t], va[t]);
            *(ushort4*)&xs[rx * S + 4 * c]  = bf4(vx[t]);
            *(ushort4*)&ps[rx * S + 4 * c]  = bf4(vp[t]);
            *(ushort4*)&as_[rx * S + 4 * c] = bf4(va[t]);
        }
        #pragma unroll
        for (int off = 8; off; off >>= 1) {
            x2 += __shfl_xor(x2, off, 16);
            n2 += __shfl_xor(n2, off, 16);
            pa += __shfl_xor(pa, off, 16);
            a2 += __shfl_xor(a2, off, 16);
        }
        if (g == 0) {
            U2s[rx] = x2;
            float un = fmaxf(__builtin_amdgcn_sqrtf(n2), EPS);
            float u2 = un * un;
            // tanh(un)/un, un ~ 0.016: series (err ~1e-8); guarded fallback
            float cc = 1.f - u2 * (1.f / 3.f) + u2 * u2 * (2.f / 15.f);
            if (un > 0.04f) cc = tanhf(un) / un;
            kcc[rx] = cc;
            kP2[rx] = cc * cc * n2;
            kPA[rx] = cc * pa;
            kAN[rx] = __builtin_amdgcn_sqrtf(a2);
        }
    }
    __syncthreads();

    // ---- MFMA: 8 waves, 4 output tiles (wb,wk), duplicate pairs split the
    // epilogue by accumulator half jh. Kdim = 256 in 8 steps. ----
    const int lane = tid & 63, wv = tid >> 6;
    const int wb = wv & 1, wk = (wv >> 1) & 1, jh = wv >> 2;
    const int m  = lane & 15, kq = lane >> 4;

    const ushort* xb = xs  + (size_t)(wb * 16 + m) * S + kq * 8;
    const ushort* pb = ps  + (size_t)(wk * 16 + m) * S + kq * 8;
    const ushort* ab = as_ + (size_t)(wk * 16 + m) * S + kq * 8;

    f32x4 accS = {0.f, 0.f, 0.f, 0.f};
    f32x4 accT = {0.f, 0.f, 0.f, 0.f};
    #pragma unroll
    for (int st = 0; st < 8; ++st) {
        short8 xa = *(const short8*)(xb + st * 32);
        short8 pf = *(const short8*)(pb + st * 32);
        short8 af = *(const short8*)(ab + st * 32);
        accS = __builtin_amdgcn_mfma_f32_16x16x32_bf16(xa, pf, accS, 0, 0, 0);
        accT = __builtin_amdgcn_mfma_f32_16x16x32_bf16(xa, af, accT, 0, 0, 0);
    }

    // constant-index extraction of this wave's accumulator half (no scratch)
    const float sA = jh ? accS[2] : accS[0];
    const float tA = jh ? accT[2] : accT[0];
    const float sB = jh ? accS[3] : accS[1];
    const float tB = jh ? accT[3] : accT[1];

    const int kloc = wk * 16 + m;
    const float cc = kcc[kloc], P2 = kP2[kloc], PA = kPA[kloc], AN = kAN[kloc];
    const int kg = k0g + kloc;
    const int r0 = wb * 16 + kq * 4 + jh * 2;   // rows jh*2 and jh*2+1 of the frag

    __builtin_nontemporal_store(
        epilogue(sA, tA, U2s[r0], cc, P2, PA, AN),
        &out[(size_t)(b0g + r0) * K + kg]);
    __builtin_nontemporal_store(
        epilogue(sB, tB, U2s[r0 + 1], cc, P2, PA, AN),
        &out[(size_t)(b0g + r0 + 1) * K + kg]);
}

extern "C" void kernel_launch(void* const* d_in, const int* in_sizes, int n_in,
                              void* d_out, int out_size, void* d_ws, size_t ws_size,
                              hipStream_t stream) {
    const float* X = (const float*)d_in[0];   // input  [B, 256]
    const float* P = (const float*)d_in[1];   // point  [128, 256]
    const float* A = (const float*)d_in[2];   // tangent[128, 256]
    float* out = (float*)d_out;

    const int B = in_sizes[0] / D;            // 2048
    const int K = in_sizes[1] / D;            // 128

    dim3 grid((B / BT) * (K / KT));           // 64 * 4 = 256 blocks
    poincare_mlr_kernel<<<grid, dim3(512), 0, stream>>>(X, P, A, out, K);
}

// Round 5
// 10.028 us; speedup vs baseline: 1.1728x; 1.1728x over previous
//
#include <hip/hip_runtime.h>
#include <hip/hip_bf16.h>
#include <math.h>

// PoincareMLR via algebraic reduction + bf16 MFMA for the two batched dots.
//   s_raw = <point_k, x_b>, t = <a_k, x_b>   (MFMA, bf16 in / f32 acc)
//   U2=|x_b|^2, cc=tanh(|point|)/|point|, P2=cc^2|point|^2, PA=cc<point,a>, AN=|a|  (fp32)
//   alpha=1-2s+U2, beta=1-P2, gamma=max(1-2s+P2*U2,EPS), s=cc*s_raw
//   |diff|^2=(alpha^2 P2 - 2 alpha beta s + beta^2 U2)/gamma^2
//   <diff,a>=(beta t - alpha PA)/gamma
//   logit = asinh(2<diff,a>/clamp_abs((1-|diff|^2)AN)) * AN
//
// R5: exact R3 structure (interleaved load/convert/store staging — low VGPR
// pressure; R4's batched loads held 48 VGPRs live and regressed) with the one
// keeper from R4: compiler __float2bfloat16 cast (packed v_cvt_pk_bf16_f32).

constexpr int D   = 256;   // feature dim
constexpr int BT  = 32;    // b rows per block
constexpr int KT  = 32;    // k rows per block
constexpr int S   = 264;   // LDS row stride in bf16 (+16B pad -> conflict-free b128)
constexpr float EPS = 1e-15f;

typedef __attribute__((ext_vector_type(8))) short short8;
typedef __attribute__((ext_vector_type(4))) float f32x4;

__device__ __forceinline__ ushort f2bf(float f) {
    union { __hip_bfloat16 h; ushort u; } cv;
    cv.h = __float2bfloat16(f);               // RNE; compiler emits v_cvt_pk_bf16_f32
    return cv.u;
}
__device__ __forceinline__ ushort4 bf4(float4 v) {
    return make_ushort4(f2bf(v.x), f2bf(v.y), f2bf(v.z), f2bf(v.w));
}
__device__ __forceinline__ float dot4(float4 a, float4 b) {
    return a.x * b.x + a.y * b.y + a.z * b.z + a.w * b.w;
}

__device__ __forceinline__ float epilogue(float s_raw, float t_raw, float U2,
                                          float cc, float P2, float PA, float AN) {
    float s     = cc * s_raw;
    float alpha = 1.f - 2.f * s + U2;
    float beta  = 1.f - P2;
    float gamma = fmaxf(1.f - 2.f * s + P2 * U2, EPS);
    float rg    = __builtin_amdgcn_rcpf(gamma);
    float nn    = alpha * alpha * P2 - 2.f * alpha * beta * s + beta * beta * U2;
    float dn2   = fmaxf(nn * rg * rg, EPS);
    float sc    = (beta * t_raw - alpha * PA) * rg;
    float draw  = (1.f - dn2) * AN;
    float den   = (draw >= 0.f ? 1.f : -1.f) * fmaxf(fabsf(draw), EPS);
    float z     = 2.f * sc * __builtin_amdgcn_rcpf(den);
    float az    = fabsf(z);
    // asinh(az) = log2(az + sqrt(az^2+1)) * ln2
    float r = __builtin_amdgcn_logf(az + __builtin_amdgcn_sqrtf(__builtin_fmaf(az, az, 1.f)))
              * 0.6931471805599453f;
    return (z >= 0.f ? r : -r) * AN;
}

__global__ __launch_bounds__(512, 2)
void poincare_mlr_kernel(const float* __restrict__ X,   // [B, D]
                         const float* __restrict__ P,   // [K, D] point
                         const float* __restrict__ A,   // [K, D] tangent
                         float* __restrict__ out,       // [B, K]
                         int K) {
    __shared__ ushort xs[BT * S];
    __shared__ ushort ps[KT * S];
    __shared__ ushort as_[KT * S];
    __shared__ float U2s[BT];
    __shared__ float kcc[KT], kP2[KT], kPA[KT], kAN[KT];

    const int tid = threadIdx.x;
    const int kb  = blockIdx.x & 3;          // K/KT = 4 k-tiles
    const int bb  = blockIdx.x >> 2;
    const int b0g = bb * BT;
    const int k0g = kb * KT;

    // ---- fused staging + per-row scalars (single global read) ----
    // thread (rx, g): rx = tid>>4 in [0,32), g = tid&15. Owns 4 float4 chunks
    // (cols g+16t) of X row rx, P row rx, A row rx. Interleaved load/convert/
    // store keeps VGPR pressure low; compiler pipelines the loads itself.
    {
        const int rx = tid >> 4, g = tid & 15;
        const float4* Xr = (const float4*)(X + (size_t)(b0g + rx) * D);
        const float4* Pr = (const float4*)(P + (size_t)(k0g + rx) * D);
        const float4* Ar = (const float4*)(A + (size_t)(k0g + rx) * D);
        float x2 = 0.f, n2 = 0.f, pa = 0.f, a2 = 0.f;
        #pragma unroll
        for (int t = 0; t < 4; ++t) {
            const int c = g + 16 * t;
            float4 vx = Xr[c];
            float4 vp = Pr[c];
            float4 va = Ar[c];
            x2 += dot4(vx, vx);
            n2 += dot4(vp, vp);
            pa += dot4(vp, va);
            a2 += dot4(va, va);
            *(ushort4*)&xs[rx * S + 4 * c]  = bf4(vx);
            *(ushort4*)&ps[rx * S + 4 * c]  = bf4(vp);
            *(ushort4*)&as_[rx * S + 4 * c] = bf4(va);
        }
        #pragma unroll
        for (int off = 8; off; off >>= 1) {
            x2 += __shfl_xor(x2, off, 16);
            n2 += __shfl_xor(n2, off, 16);
            pa += __shfl_xor(pa, off, 16);
            a2 += __shfl_xor(a2, off, 16);
        }
        if (g == 0) {
            U2s[rx] = x2;
            float un = fmaxf(__builtin_amdgcn_sqrtf(n2), EPS);
            float u2 = un * un;
            // tanh(un)/un, un ~ 0.016: series (err ~1e-8); guarded fallback
            float cc = 1.f - u2 * (1.f / 3.f) + u2 * u2 * (2.f / 15.f);
            if (un > 0.04f) cc = tanhf(un) / un;
            kcc[rx] = cc;
            kP2[rx] = cc * cc * n2;
            kPA[rx] = cc * pa;
            kAN[rx] = __builtin_amdgcn_sqrtf(a2);
        }
    }
    __syncthreads();

    // ---- MFMA: 8 waves, 4 output tiles (wb,wk), duplicate pairs split the
    // epilogue by accumulator half jh. Kdim = 256 in 8 steps. ----
    const int lane = tid & 63, wv = tid >> 6;
    const int wb = wv & 1, wk = (wv >> 1) & 1, jh = wv >> 2;
    const int m  = lane & 15, kq = lane >> 4;

    const ushort* xb = xs  + (size_t)(wb * 16 + m) * S + kq * 8;
    const ushort* pb = ps  + (size_t)(wk * 16 + m) * S + kq * 8;
    const ushort* ab = as_ + (size_t)(wk * 16 + m) * S + kq * 8;

    f32x4 accS = {0.f, 0.f, 0.f, 0.f};
    f32x4 accT = {0.f, 0.f, 0.f, 0.f};
    #pragma unroll
    for (int st = 0; st < 8; ++st) {
        short8 xa = *(const short8*)(xb + st * 32);
        short8 pf = *(const short8*)(pb + st * 32);
        short8 af = *(const short8*)(ab + st * 32);
        accS = __builtin_amdgcn_mfma_f32_16x16x32_bf16(xa, pf, accS, 0, 0, 0);
        accT = __builtin_amdgcn_mfma_f32_16x16x32_bf16(xa, af, accT, 0, 0, 0);
    }

    // constant-index extraction of this wave's accumulator half (no scratch)
    const float sA = jh ? accS[2] : accS[0];
    const float tA = jh ? accT[2] : accT[0];
    const float sB = jh ? accS[3] : accS[1];
    const float tB = jh ? accT[3] : accT[1];

    const int kloc = wk * 16 + m;
    const float cc = kcc[kloc], P2 = kP2[kloc], PA = kPA[kloc], AN = kAN[kloc];
    const int kg = k0g + kloc;
    const int r0 = wb * 16 + kq * 4 + jh * 2;   // rows jh*2 and jh*2+1 of the frag

    out[(size_t)(b0g + r0) * K + kg]     = epilogue(sA, tA, U2s[r0],     cc, P2, PA, AN);
    out[(size_t)(b0g + r0 + 1) * K + kg] = epilogue(sB, tB, U2s[r0 + 1], cc, P2, PA, AN);
}

extern "C" void kernel_launch(void* const* d_in, const int* in_sizes, int n_in,
                              void* d_out, int out_size, void* d_ws, size_t ws_size,
                              hipStream_t stream) {
    const float* X = (const float*)d_in[0];   // input  [B, 256]
    const float* P = (const float*)d_in[1];   // point  [128, 256]
    const float* A = (const float*)d_in[2];   // tangent[128, 256]
    float* out = (float*)d_out;

    const int B = in_sizes[0] / D;            // 2048
    const int K = in_sizes[1] / D;            // 128

    dim3 grid((B / BT) * (K / KT));           // 64 * 4 = 256 blocks
    poincare_mlr_kernel<<<grid, dim3(512), 0, stream>>>(X, P, A, out, K);
}